// Round 9
// baseline (65.236 us; speedup 1.0000x reference)
//
#include <hip/hip_runtime.h>
#include <hip/hip_bf16.h>
#include <stdint.h>

#define MB_ 16384
#define NN_ 1024
#define KK_ 1024

typedef __bf16 bhalf;
typedef __bf16 bhalf8 __attribute__((ext_vector_type(8)));
typedef __bf16 bhalf4 __attribute__((ext_vector_type(4)));
typedef float f32x4 __attribute__((ext_vector_type(4)));

typedef const __attribute__((address_space(1))) void* gas_ptr;
typedef __attribute__((address_space(3))) void* las_ptr;

__device__ __forceinline__ void gload_lds16(const void* g, void* l) {
  __builtin_amdgcn_global_load_lds((gas_ptr)g, (las_ptr)l, 16, 0, 0);
}

// ---------------- K1a: partial column max / sumexp (over rows, per column) ----------------
__global__ void k_colpart(const float* __restrict__ W,
                          float* __restrict__ pM, float* __restrict__ pS) {
  int col = blockIdx.x * 256 + threadIdx.x;
  int rc  = blockIdx.y;
  const float* p = W + (size_t)rc * 32 * NN_ + col;
  float v[32];
#pragma unroll
  for (int i = 0; i < 32; ++i) v[i] = p[(size_t)i * NN_];
  float m = v[0];
#pragma unroll
  for (int i = 1; i < 32; ++i) m = fmaxf(m, v[i]);
  float s = 0.f;
#pragma unroll
  for (int i = 0; i < 32; ++i) s += __expf(v[i] - m);
  pM[rc * NN_ + col] = m;
  pS[rc * NN_ + col] = s;
}

// ---------------- K1b: combine partials -> colLSE ----------------
__global__ void k_colfin(const float* __restrict__ pM, const float* __restrict__ pS,
                         float* __restrict__ colLSE) {
  int col = blockIdx.x * 256 + threadIdx.x;
  float m = -1e30f;
#pragma unroll
  for (int i = 0; i < 32; ++i) m = fmaxf(m, pM[i * NN_ + col]);
  float s = 0.f;
#pragma unroll
  for (int i = 0; i < 32; ++i) s += pS[i * NN_ + col] * __expf(pM[i * NN_ + col] - m);
  colLSE[col] = m + __logf(s);
}

// ---------------- K2: eA[i,k] = exp(W[i,k]-colLSE[k]) ----------------
__global__ void k_expA(const float* __restrict__ W, const float* __restrict__ colLSE,
                       bhalf* __restrict__ eA) {
  int i = blockIdx.x;
  int l = threadIdx.x;
  const float4* row = (const float4*)(W + (size_t)i * NN_);
  const float4* cls = (const float4*)colLSE;
#pragma unroll
  for (int t = 0; t < 4; ++t) {
    float4 wv = row[t * 64 + l];
    float4 cv = cls[t * 64 + l];
    bhalf4 o;
    o[0] = (bhalf)__expf(wv.x - cv.x);
    o[1] = (bhalf)__expf(wv.y - cv.y);
    o[2] = (bhalf)__expf(wv.z - cv.z);
    o[3] = (bhalf)__expf(wv.w - cv.w);
    *(bhalf4*)(eA + (size_t)i * NN_ + t * 256 + l * 4) = o;
  }
}

// ---------------- GEMM: out[b,i] = log( sum_k exp(la[b,k]) * eA[i,k] ) ----------------
// 256x256 tile, BK=32, 512 thr (8 waves 2Mx4N). ONE phase per K-tile:
//   top: issue A(t+1) 4x dwordx4 + B(t+1) 2x gload_lds (into buf^1), 12 ds_read_b128
//   barrier; lgkmcnt(0); 32 independent MFMA (one per acc element, kk=1)
//   vmcnt(2) -> cvt A(t+1) (16 exp -> 2 ds_write_b128, swizzled); lgkmcnt(0);
//   vmcnt(0) -> B(t+1) published; barrier.
// 2 barriers / 32 MFMA (vs 2/16 before). LDS 64KB: A dbuf [0,32K), B dbuf [32K,64K).
// Chunk swizzle both sides: stored_chunk = chunk ^ ((row>>1)&3); B source pre-swizzled.

#define VMW(N)  asm volatile("s_waitcnt vmcnt(" #N ")" ::: "memory")
#define LGKM0   asm volatile("s_waitcnt lgkmcnt(0)" ::: "memory")
#define HINT8   asm volatile("s_waitcnt lgkmcnt(8)" ::: "memory")
#define SBAR    __builtin_amdgcn_s_barrier()
#define SCB0    __builtin_amdgcn_sched_barrier(0)
#define NOPS    ((void)0)

// B: 16KB/tile, 2 gload_lds16/thread, linear dest, pre-swizzled source.
#define STB(OB, T) do {                                                       \
    const bhalf* g_ = pgB + (T) * 32;                                         \
    unsigned char* d_ = lds + 32768 + (OB) * 16384 + tid * 16;                \
    gload_lds16(g_, d_); gload_lds16(g_ + 131072, d_ + 8192); } while (0)

// A: 32KB f32/tile, 4 coalesced dwordx4/thread (thread = row tid>>1, half tid&1)
#define LOADA(T) do {                                                         \
    _Pragma("unroll")                                                         \
    for (int j_ = 0; j_ < 4; ++j_) va[j_] = pLA4[(T) * 8 + j_]; } while (0)

// exp + pack 16 f32 -> 2 swizzled ds_write_b128
#define CVTA(OB) do {                                                         \
    unsigned char* d_ = lds + (OB) * 16384 + dA_off;                          \
    bhalf8 o0, o1;                                                            \
    o0[0] = (bhalf)__expf(va[0].x); o0[1] = (bhalf)__expf(va[0].y);           \
    o0[2] = (bhalf)__expf(va[0].z); o0[3] = (bhalf)__expf(va[0].w);           \
    o0[4] = (bhalf)__expf(va[1].x); o0[5] = (bhalf)__expf(va[1].y);           \
    o0[6] = (bhalf)__expf(va[1].z); o0[7] = (bhalf)__expf(va[1].w);           \
    o1[0] = (bhalf)__expf(va[2].x); o1[1] = (bhalf)__expf(va[2].y);           \
    o1[2] = (bhalf)__expf(va[2].z); o1[3] = (bhalf)__expf(va[2].w);           \
    o1[4] = (bhalf)__expf(va[3].x); o1[5] = (bhalf)__expf(va[3].y);           \
    o1[6] = (bhalf)__expf(va[3].z); o1[7] = (bhalf)__expf(va[3].w);           \
    *(bhalf8*)(d_ + aw0) = o0; *(bhalf8*)(d_ + aw1) = o1; } while (0)

// LT/BT: k-tile offsets rel. current base (-1 none). WA: post-MFMA wait (A landed).
// WB: pre-barrier wait (B published). CV: cvt A(t+1) -> LDS buf BUF^1.
#define KTILE(BUF, LT, BT, WA, WB, CV)                                        \
  {                                                                           \
    bhalf8 af[8]; bhalf8 bq[4];                                               \
    if ((LT) >= 0) LOADA(LT);                                                 \
    if ((BT) >= 0) STB((BUF) ^ 1, BT);                                        \
    _Pragma("unroll")                                                         \
    for (int m_ = 0; m_ < 8; ++m_)                                            \
      af[m_] = *(const bhalf8*)(pA + (BUF) * 16384 + m_ * 1024);              \
    _Pragma("unroll")                                                         \
    for (int n_ = 0; n_ < 4; ++n_)                                            \
      bq[n_] = *(const bhalf8*)(pB + (BUF) * 16384 + n_ * 1024);              \
    HINT8;                                                                    \
    SCB0; SBAR; LGKM0; SCB0;                                                  \
    __builtin_amdgcn_s_setprio(1);                                            \
    _Pragma("unroll")                                                         \
    for (int m_ = 0; m_ < 8; ++m_)                                            \
      _Pragma("unroll")                                                       \
      for (int n_ = 0; n_ < 4; ++n_)                                          \
        acc[m_][n_] = __builtin_amdgcn_mfma_f32_16x16x32_bf16(                \
            af[m_], bq[n_], acc[m_][n_], 0, 0, 0);                            \
    __builtin_amdgcn_s_setprio(0);                                            \
    WA;                                                                       \
    if (CV) { CVTA((BUF) ^ 1); LGKM0; }                                       \
    WB;                                                                       \
    SCB0; SBAR;                                                               \
  }

__global__ __launch_bounds__(512, 2) void k_gemm(const float* __restrict__ LA, // [M][K] f32
                                                 const bhalf* __restrict__ Bt, // eA [N][K]
                                                 float* __restrict__ out) {
  __shared__ __align__(16) unsigned char lds[65536];

  const int nwg = gridDim.x;              // 256, %8==0
  const int wg  = blockIdx.x;
  const int swz = (wg & 7) * (nwg >> 3) + (wg >> 3);
  const int bm = swz >> 2;                // 0..63
  const int bn = swz & 3;                 // 0..3

  const int tid = threadIdx.x;
  const int l = tid & 63;
  const int w = tid >> 6;
  const int wr = w >> 2;                  // 0..1 (M)
  const int wc = w & 3;                   // 0..3 (N)

  // B staging: dest row = call*128 + (tid>>2), stored chunk cs = tid&3;
  // source logical chunk = cs ^ ((row>>1)&3) = (tid&3) ^ ((tid>>3)&3).
  const bhalf* pgB = Bt + (size_t)(bn * 256 + (tid >> 2)) * KK_ +
                     (((tid & 3) ^ ((tid >> 3) & 3)) << 3);

  // A staging: row ar = tid>>1 (0..255), k-half h = tid&1 (16 f32, chunks 2h,2h+1)
  const int ar = tid >> 1;
  const int h  = tid & 1;
  const float4* pLA4 = (const float4*)(LA + (size_t)(bm * 256 + ar) * KK_) + h * 4;
  const int dA_off = ar * 64;
  const int sA = (ar >> 1) & 3;
  const int aw0 = ((2 * h) ^ sA) << 4;
  const int aw1 = ((2 * h + 1) ^ sA) << 4;

  // fragment read bases: row = {wr*128|wc*64} + frag*16 + (l&15); chunk = l>>4;
  // stored chunk = (l>>4) ^ (((l&15)>>1)&3)  (frag*16 doesn't affect (row>>1)&3)
  const int cs16 = (((l >> 4) ^ (((l & 15) >> 1) & 3)) << 4);
  const unsigned char* pA = lds + (wr * 128 + (l & 15)) * 64 + cs16;
  const unsigned char* pB = lds + 32768 + (wc * 64 + (l & 15)) * 64 + cs16;

  f32x4 zero = {0.f, 0.f, 0.f, 0.f};
  f32x4 acc[8][4];
#pragma unroll
  for (int m = 0; m < 8; ++m)
#pragma unroll
    for (int n = 0; n < 4; ++n) acc[m][n] = zero;

  float4 va[4];

  // prologue (queue oldest->newest): A(0)4, B(0)2 -> VMW(2) retires A(0) -> cvt buf0;
  // A(1)4, B(1)2 -> VMW(6) retires B(0); A(1)+B(1) stay in flight.
  LOADA(0);
  STB(0, 0);
  VMW(2);
  CVTA(0);
  LOADA(1);
  STB(1, 1);
  VMW(6);
  LGKM0;
  SBAR;

  // tile 0 (buf0): A(1)/B(1) already issued; cvt A(1)->buf1 after VMW(2)
  KTILE(0, -1, -1, VMW(2), VMW(0), 1)

  // tiles 1..30: 15 pairs; base advances 2 k-tiles per pair
  for (int p = 0; p < 15; ++p) {
    KTILE(1, 2, 2, VMW(2), VMW(0), 1)
    KTILE(0, 3, 3, VMW(2), VMW(0), 1)
    pLA4 += 16;   // 2 tiles * 8 float4
    pgB  += 64;   // 2 tiles * 32 bf16
  }
  // tile 31 (buf1): pure compute
  KTILE(1, -1, -1, NOPS, NOPS, 0)

  // epilogue: out = log(acc). D row = 4*(l>>4)+r (+16/mf), col = l&15 (+16/nf)
  const int c0 = bn * 256 + wc * 64 + (l & 15);
  const int r0 = bm * 256 + wr * 128 + (l >> 4) * 4;
#pragma unroll
  for (int mf = 0; mf < 8; ++mf) {
#pragma unroll
    for (int r = 0; r < 4; ++r) {
      const int row = r0 + mf * 16 + r;
      float* o = out + (size_t)row * NN_ + c0;
#pragma unroll
      for (int nf = 0; nf < 4; ++nf)
        o[nf * 16] = __logf(acc[mf][nf][r]);
    }
  }
}

extern "C" void kernel_launch(void* const* d_in, const int* in_sizes, int n_in,
                              void* d_out, int out_size, void* d_ws, size_t ws_size,
                              hipStream_t stream) {
  const float* log_alpha = (const float*)d_in[0];  // [16384,1024] f32
  const float* W         = (const float*)d_in[1];  // [1024,1024] f32
  float* out = (float*)d_out;                      // [16384,1024] f32

  uintptr_t ws = (uintptr_t)d_ws;
  bhalf* eA     = (bhalf*)(ws);                    // 2,097,152 B
  float* colLSE = (float*)(ws + 2097152);          //     4,096 B
  float* pM     = (float*)(ws + 2101248);          //   131,072 B
  float* pS     = (float*)(ws + 2232320);          //   131,072 B

  k_colpart<<<dim3(4, 32), 256, 0, stream>>>(W, pM, pS);
  k_colfin<<<4, 256, 0, stream>>>(pM, pS, colLSE);
  k_expA<<<NN_, 64, 0, stream>>>(W, colLSE, eA);
  k_gemm<<<(MB_ / 256) * (NN_ / 256), 512, 0, stream>>>(log_alpha, eA, out);
}